// Round 2
// baseline (375.173 us; speedup 1.0000x reference)
//
#include <hip/hip_runtime.h>
#include <cfloat>
#include <cstdint>

#define NN 8192      // nodes
#define DD 128       // features
#define WPR 256      // bitmask words per row (8192/32)
#define TOPK 32
#define PRE 12       // probes resolved with batched (latency-overlapped) loads

// monotonic float -> uint mapping (descending float == descending uint)
__device__ __forceinline__ uint32_t f2s(float f) {
  uint32_t u = __float_as_uint(f);
  return (u & 0x80000000u) ? ~u : (u | 0x80000000u);
}
__device__ __forceinline__ float s2f(uint32_t s) {
  return (s & 0x80000000u) ? __uint_as_float(s & 0x7fffffffu)
                           : __uint_as_float(~s);
}
__device__ __forceinline__ unsigned long long shfl_down_u64(unsigned long long v, int off) {
  unsigned lo = __shfl_down((unsigned)(v & 0xffffffffull), off, 64);
  unsigned hi = __shfl_down((unsigned)(v >> 32), off, 64);
  return ((unsigned long long)hi << 32) | (unsigned long long)lo;
}

// Permuted bitmask layout (prep encode == probe decode, both derived from):
//   column idx: g = idx>>8 (256-col group), p = idx&3 (uint4 component),
//               l = (idx>>2)&63 (lane), h = l>>5, i = l&31
//   word  w = g*8 + p*2 + h,  bit i
// Fallback decode: col = ((w>>3)<<8) | ((w&1)<<7) | (i<<2) | ((w>>1)&3)

// Fused prep kernel:
//   blocks [0, DD)           : exact top-32 (value, index) per feature column, descending
//   blocks [DD, DD+NN/4)     : 4 adj rows per block, one WAVE per row:
//                              wave-coalesced uint4 loads (1KB/instr) + __ballot bit build
__global__ __launch_bounds__(256) void prep_kernel(
    const float* __restrict__ x, const int* __restrict__ adj,
    uint32_t* __restrict__ bits, int* __restrict__ has_nbr,
    float* __restrict__ tkv, int* __restrict__ tki) {
  const int b = blockIdx.x;
  const int t = threadIdx.x;

  __shared__ unsigned long long red[4];
  __shared__ unsigned long long bcast;

  if (b >= DD) {
    // ---- bitmask build: one wave per adjacency row, fully coalesced ----
    const int lane = t & 63;
    const int row = (b - DD) * 4 + (t >> 6);
    const uint4* rp = (const uint4*)(adj + (size_t)row * NN);
    uint32_t acc0 = 0, acc1 = 0, acc2 = 0, acc3 = 0;
    unsigned long long any = 0ull;
    const int oct = lane >> 3;   // which iteration-of-8 this lane harvests
    const int s = lane & 7;      // slot within the 8 words of a group
#pragma unroll
    for (int g = 0; g < 32; ++g) {
      uint4 v = rp[g * 64 + lane];                 // 1KB contiguous per wave instr
      unsigned long long b0 = __ballot(v.x != 0);  // cols g*256 + 4i + 0
      unsigned long long b1 = __ballot(v.y != 0);  // cols g*256 + 4i + 1
      unsigned long long b2 = __ballot(v.z != 0);
      unsigned long long b3 = __ballot(v.w != 0);
      any |= (b0 | b1 | b2 | b3);
      if (oct == (g & 7)) {
        unsigned long long bb = (s & 4) ? ((s & 2) ? b3 : b2)
                                        : ((s & 2) ? b1 : b0);
        uint32_t word = (s & 1) ? (uint32_t)(bb >> 32) : (uint32_t)bb;
        switch (g >> 3) {        // compile-time after unroll
          case 0: acc0 = word; break;
          case 1: acc1 = word; break;
          case 2: acc2 = word; break;
          case 3: acc3 = word; break;
        }
      }
    }
    // lane l holds words {l, 64+l, 128+l, 192+l} -> coalesced 256B stores
    uint32_t* ob = bits + (size_t)row * WPR;
    ob[lane] = acc0;
    ob[64 + lane] = acc1;
    ob[128 + lane] = acc2;
    ob[192 + lane] = acc3;
    if (lane == 0) has_nbr[row] = (any != 0ull) ? 1 : 0;
  } else {
    // ---- exact top-32 of column x[:, d], descending (unchanged, proven) ----
    const int d = b;
    float vals[32];
#pragma unroll
    for (int e = 0; e < 32; ++e) {
      int j = t * 32 + e;
      vals[e] = x[(size_t)j * DD + d];
    }
    unsigned long long prev = ~0ull;          // keys strictly below prev each round
    for (int k = 0; k < TOPK; ++k) {
      unsigned long long best = 0ull;
#pragma unroll
      for (int e = 0; e < 32; ++e) {
        int j = t * 32 + e;
        unsigned long long key =
            ((unsigned long long)f2s(vals[e]) << 32) | (unsigned)j;
        if (key < prev && key > best) best = key;
      }
      // wave reduce (64 lanes)
      for (int off = 32; off; off >>= 1) {
        unsigned long long o = shfl_down_u64(best, off);
        if (o > best) best = o;
      }
      const int lane = t & 63, wv = t >> 6;
      if (lane == 0) red[wv] = best;
      __syncthreads();
      if (t == 0) {
        unsigned long long m = red[0];
        for (int i = 1; i < 4; ++i) if (red[i] > m) m = red[i];
        bcast = m;
        uint32_t s = (uint32_t)(m >> 32);
        uint32_t j = (uint32_t)(m & 0xffffffffu);
        tkv[k * DD + d] = s2f(s);
        tki[k * DD + d] = (int)j;
      }
      __syncthreads();
      prev = bcast;
    }
  }
}

// Probe kernel: 2 rows per block; wave = 64 features of one row.
// Batches the first PRE candidate probes as independent loads (one latency wait),
// resolves first-hit in registers; serial tail only for unresolved waves (~1.6%).
__global__ __launch_bounds__(256) void probe_kernel(
    const float* __restrict__ x, const uint32_t* __restrict__ bits,
    const int* __restrict__ has_nbr, const float* __restrict__ tkv,
    const int* __restrict__ tki, float* __restrict__ out) {
  const int t = threadIdx.x;
  const int row = blockIdx.x * 2 + (t >> 7);
  const int d = t & 127;
  const uint32_t* rb = bits + (size_t)row * WPR;

  int idxs[PRE];
#pragma unroll
  for (int k = 0; k < PRE; ++k) idxs[k] = tki[k * DD + d];   // coalesced, L1-broadcast
  uint32_t wrd[PRE];
#pragma unroll
  for (int k = 0; k < PRE; ++k) {                            // independent -> overlapped
    int idx = idxs[k];
    wrd[k] = rb[((idx >> 8) << 3) | ((idx & 3) << 1) | ((idx >> 7) & 1)];
  }
  float res = 0.0f;
  bool done = false;
#pragma unroll
  for (int k = 0; k < PRE; ++k) {
    int idx = idxs[k];
    bool hit = (wrd[k] >> ((idx >> 2) & 31)) & 1u;
    if (!done && hit) { res = tkv[k * DD + d]; done = true; }
  }
  for (int k = PRE; k < TOPK; ++k) {
    if (__all((int)done)) break;              // wave-uniform early exit
    int idx = tki[k * DD + d];
    float val = tkv[k * DD + d];
    uint32_t w = rb[((idx >> 8) << 3) | ((idx & 3) << 1) | ((idx >> 7) & 1)];
    bool hit = (w >> ((idx >> 2) & 31)) & 1u;
    if (!done && hit) { res = val; done = true; }
  }
  if (__any((int)(!done))) {
    // rare (~2^-32 per element): neighbors exist but none in top-32 -> full scan
    if (!done && has_nbr[row]) {
      float m = -FLT_MAX;
      for (int wd = 0; wd < WPR; ++wd) {
        uint32_t bm = rb[wd];
        int base = ((wd >> 3) << 8) | ((wd & 1) << 7) | ((wd >> 1) & 3);
        while (bm) {
          int i = __ffs(bm) - 1;
          bm &= bm - 1;
          int j = base + (i << 2);
          m = fmaxf(m, x[(size_t)j * DD + d]);
        }
      }
      res = m;
    }
    // !done && !has_nbr -> res stays 0 (matches reference)
  }
  out[(size_t)row * DD + d] = res;
}

extern "C" void kernel_launch(void* const* d_in, const int* in_sizes, int n_in,
                              void* d_out, int out_size, void* d_ws, size_t ws_size,
                              hipStream_t stream) {
  const float* x = (const float*)d_in[0];   // [8192,128] f32
  const int* adj = (const int*)d_in[1];     // [8192,8192] i32
  float* out = (float*)d_out;               // [8192,128] f32

  // workspace layout (8.06 MB total)
  uint32_t* bits = (uint32_t*)d_ws;                                   // 8 MB
  int* has_nbr = (int*)((char*)d_ws + (size_t)NN * WPR * 4);          // 32 KB
  float* tkv = (float*)((char*)has_nbr + (size_t)NN * 4);             // 16 KB
  int* tki = (int*)((char*)tkv + (size_t)TOPK * DD * 4);              // 16 KB

  prep_kernel<<<DD + NN / 4, 256, 0, stream>>>(x, adj, bits, has_nbr, tkv, tki);
  probe_kernel<<<NN / 2, 256, 0, stream>>>(x, bits, has_nbr, tkv, tki, out);
}